// Round 13
// baseline (846.797 us; speedup 1.0000x reference)
//
#include <hip/hip_runtime.h>

#define H 181
#define T_LEN 1024
#define BB 4             // batch rows per block
#define NBLK 256         // 256 * 4 = 1024; one block per CU (LDS-pinned)
#define NTHR 768         // 12 waves, 3 per SIMD
#define KT3 3            // k-tiles of 64 -> 192 >= 181
#define FRAGB 1024       // bytes per kt fragment (64 lanes x 16 B)
#define PST 192          // unit stride (wsc, FC)
#define PSTI 200         // raw-acc publish stride in dwords (2-way banks = free)

typedef __attribute__((ext_vector_type(4))) int   intx4;
typedef __attribute__((ext_vector_type(4))) float floatx4;

#define LOG2E 1.4426950408889634f
// Schraudolph exp2 (balanced sawtooth, |rel err| <= ~3%), clamped to [-20,14]
#define SCH_C  1064992506.0f
#define SCH_LO 897220352.0f
#define SCH_HI 1182433024.0f

__device__ __forceinline__ float exp2_fast(float g) {
    float s = fmaf(g, 8388608.0f, SCH_C);
    s = fminf(fmaxf(s, SCH_LO), SCH_HI);
    return __uint_as_float((unsigned)s);
}
__device__ __forceinline__ float rcpf(float x)   { return __builtin_amdgcn_rcpf(x); }
__device__ __forceinline__ float exp2hw(float x) { return __builtin_amdgcn_exp2f(x); }

// 256 persistent blocks x 4 batch (ALL 256 CUs). Two-phase step:
//  P1 (wave = gate x 3 unit-tiles): 3 b128 i8 h-frag reads -> 9
//     mfma_i32_16x16x64_i8 -> publish RAW i32 accs (b128, stride 200 dw,
//     2-way banks). NO dequant here: R12 did it exec-masked (4/64 lanes)
//     costing ~720 cy/CU/step of issue for 144 values.
//  P2 (lane = one (unit,batch) triple, dense): 3 b32 acc reads -> dequant
//     via preloaded per-unit consts (6 dense instrs) -> gates (r Schraudolph,
//     z/n exact exp, grouped rcp) -> h update -> i8 quant -> DPP quad-pack
//     -> one b32 per 4 lanes into the MFMA B-frag slot.
__launch_bounds__(NTHR, 3)
__global__ void gru_i8(const float* __restrict__ x,
                       const float* __restrict__ w_ih,
                       const float* __restrict__ w_hh,
                       const float* __restrict__ b_ih,
                       const float* __restrict__ b_hh,
                       const float* __restrict__ w_fc,
                       const float* __restrict__ b_fc,
                       float* __restrict__ out) {
    __shared__ __align__(16) char  hfr_s[2 * KT3 * FRAGB];  // 6 KB i8 h dbuf
    __shared__ __align__(16) int   pre_i[3 * BB * PSTI];    // 9.6 KB raw accs
    __shared__ __align__(16) float x_s[BB * T_LEN];         // 16 KB x; reused for FC
    __shared__ float wsc_s[3 * PST];                        // w_hh row scales
    __shared__ volatile char pad_s[47600];                  // total > 80 KB: pin 1 block/CU

    const int tid  = threadIdx.x;
    const int wv   = tid >> 6;
    const int lane = tid & 63;
    const int col  = lane & 15;
    const int q    = lane >> 4;
    const int b0   = blockIdx.x * BB;
    if (tid == 0) pad_s[0] = 0;

    // ================= phase-1 identity: gate g, tile group tg =================
    const int g  = wv >> 2;          // 0..2
    const int tg = wv & 3;           // 0..3 ; tiles tg*3+{0,1,2}

    // ---- A fragments: per-row int8 w_hh, 3 tiles x 3 kt ----
    intx4 afr[3][KT3];
    #pragma unroll
    for (int u = 0; u < 3; ++u) {
        const int  mu = (tg * 3 + u) * 16 + col;
        const bool mv = (mu < H);
        const float* wrow = w_hh + (size_t)(g * H + (mv ? mu : 0)) * H;
        float rm = 0.0f;
        if (mv) for (int k = 0; k < H; ++k) rm = fmaxf(rm, fabsf(wrow[k]));
        float s    = (rm > 1e-30f) ? rm * (1.0f / 127.0f) : 1.0f;
        float invs = 1.0f / s;
        #pragma unroll
        for (int kt = 0; kt < KT3; ++kt) {
            union { signed char c[16]; intx4 v; } uu;
            #pragma unroll
            for (int e = 0; e < 16; ++e) {
                int k = kt * 64 + q * 16 + e;
                float v = (mv && k < H) ? wrow[k] * invs : 0.0f;
                v = fminf(fmaxf(rintf(v), -127.0f), 127.0f);
                uu.c[e] = (signed char)(int)v;
            }
            afr[u][kt] = uu.v;
        }
        if (q == 0) wsc_s[g * PST + mu] = s;
    }

    // ---- stage x; zero h frag buffers ----
    for (int i = tid; i < BB * T_LEN; i += NTHR)
        x_s[i] = x[(size_t)b0 * T_LEN + i];
    {
        int* hz = (int*)hfr_s;
        for (int i = tid; i < 2 * KT3 * FRAGB / 4; i += NTHR) hz[i] = 0;
    }
    __syncthreads();   // wsc_s ready

    // ================= phase-2 identity: one triple per lane =================
    const int  gb = wv / 3;                 // batch 0..3 (wave-uniform)
    const int  gj = (wv % 3) * 64 + lane;   // unit 0..191
    const bool jv = (gj < H);
    // dense per-lane dequant consts + gate weights (step-invariant registers)
    const float dqR = -LOG2E * wsc_s[0 * PST + gj] * (1.0f / 127.0f);
    const float dqZ = -LOG2E * wsc_s[1 * PST + gj] * (1.0f / 127.0f);
    const float dqN =  2.0f * LOG2E * wsc_s[2 * PST + gj] * (1.0f / 127.0f);
    const float baseR = jv ? -LOG2E * (b_ih[gj] + b_hh[gj])               : 0.0f;
    const float baseZ = jv ? -LOG2E * (b_ih[H + gj] + b_hh[H + gj])       : 0.0f;
    const float baseN = jv ?  2.0f * LOG2E * b_hh[2 * H + gj]             : 0.0f;
    const float wrS = jv ? -LOG2E * w_ih[gj]                : 0.0f;
    const float wzS = jv ? -LOG2E * w_ih[H + gj]            : 0.0f;
    const float wnS = jv ?  2.0f * LOG2E * w_ih[2 * H + gj] : 0.0f;
    const float bnI = jv ?  2.0f * LOG2E * b_ih[2 * H + gj] : 0.0f;
    // h-frag slot for this lane's quad (leader lane&3==0 writes 4 units)
    const int hoff  = (gj >> 6) * FRAGB + (((gj >> 4) & 3) * 16 + gb) * 16 + (gj & 15);
    const int rbase = lane * 16;

    float h = 0.0f;

    auto step = [&](const char* rb, char* wb, int t) {
        // ---------- phase 1: MFMA + raw-acc publish ----------
        intx4 bf[KT3];
        #pragma unroll
        for (int kt = 0; kt < KT3; ++kt)
            bf[kt] = *(const intx4*)(rb + kt * FRAGB + rbase);
        intx4 acc[3] = {{0,0,0,0}, {0,0,0,0}, {0,0,0,0}};
        #pragma unroll
        for (int kt = 0; kt < KT3; ++kt) {
            acc[0] = __builtin_amdgcn_mfma_i32_16x16x64_i8(afr[0][kt], bf[kt], acc[0], 0, 0, 0);
            acc[1] = __builtin_amdgcn_mfma_i32_16x16x64_i8(afr[1][kt], bf[kt], acc[1], 0, 0, 0);
            acc[2] = __builtin_amdgcn_mfma_i32_16x16x64_i8(afr[2][kt], bf[kt], acc[2], 0, 0, 0);
        }
        if (col < BB) {
            #pragma unroll
            for (int u = 0; u < 3; ++u)
                *(intx4*)&pre_i[(g * BB + col) * PSTI + (tg * 3 + u) * 16 + q * 4] = acc[u];
        }
        __syncthreads();

        // ---------- phase 2: dense dequant + gates (1 triple/lane) ----------
        float pR = fmaf((float)pre_i[(0 * BB + gb) * PSTI + gj], dqR, baseR);
        float pZ = fmaf((float)pre_i[(1 * BB + gb) * PSTI + gj], dqZ, baseZ);
        float pN = fmaf((float)pre_i[(2 * BB + gb) * PSTI + gj], dqN, baseN);
        float xv = x_s[gb * T_LEN + t];

        float er = exp2_fast(fmaf(xv, wrS, pR));
        float ez = exp2hw(fminf(fmaf(xv, wzS, pZ), 14.0f));
        float dR = 1.0f + er, dZ = 1.0f + ez;
        float qq = rcpf(dR * dZ);
        float rr = qq * dZ, zz = qq * dR;
        float gn = fmaf(rr, pN, fmaf(xv, wnS, bnI));
        float en = exp2hw(fminf(gn, 30.0f));
        float nn = fmaf(-2.0f, rcpf(1.0f + en), 1.0f);  // tanh
        h = fmaf(zz, h - nn, nn);                        // |h|<1

        int iq  = (int)rintf(h * 127.0f);
        int v32 = jv ? (iq & 255) : 0;
        // DPP quad-pack: 4 consecutive lanes' bytes -> leader's b32
        int u1  = __builtin_amdgcn_update_dpp(0, v32, 0xB1, 0xF, 0xF, true); // qp[1,0,3,2]
        int p01 = __builtin_amdgcn_perm(u1, v32, 0x05010400);
        int u2  = __builtin_amdgcn_update_dpp(0, p01, 0x4E, 0xF, 0xF, true); // qp[2,3,0,1]
        int pq  = __builtin_amdgcn_perm(u2, p01, 0x05040100);
        if ((lane & 3) == 0)
            *(int*)(wb + (hoff & ~15) + (gj & 15)) = pq;
        __syncthreads();
    };

    char* buf0 = hfr_s;
    char* buf1 = hfr_s + KT3 * FRAGB;
    for (int t = 0; t < T_LEN; t += 2) {
        step(buf0, buf1, t);
        step(buf1, buf0, t + 1);
    }

    // ---- final FC: publish h (f32) into x_s, 40 lanes reduce ----
    __syncthreads();
    x_s[gb * PST + gj] = h;
    __syncthreads();
    if (tid < BB * 10) {
        int bb = tid / 10, c = tid % 10;
        float acc = b_fc[c];
        for (int k = 0; k < H; ++k)
            acc = fmaf(x_s[bb * PST + k], w_fc[c * H + k], acc);
        out[(b0 + bb) * 10 + c] = acc;
    }
}

extern "C" void kernel_launch(void* const* d_in, const int* in_sizes, int n_in,
                              void* d_out, int out_size, void* d_ws, size_t ws_size,
                              hipStream_t stream) {
    const float* x    = (const float*)d_in[0];
    const float* w_ih = (const float*)d_in[1];
    const float* w_hh = (const float*)d_in[2];
    const float* b_ih = (const float*)d_in[3];
    const float* b_hh = (const float*)d_in[4];
    const float* w_fc = (const float*)d_in[5];
    const float* b_fc = (const float*)d_in[6];
    float* out = (float*)d_out;

    gru_i8<<<NBLK, NTHR, 0, stream>>>(x, w_ih, w_hh, b_ih, b_hh, w_fc, b_fc, out);
}

// Round 14
// 715.000 us; speedup vs baseline: 1.1843x; 1.1843x over previous
//
#include <hip/hip_runtime.h>

#define H 181
#define T_LEN 1024
#define BB 4             // batch rows per block
#define NBLK 256         // 256 * 4 = 1024; one block per CU (LDS-pinned)
#define NTHR 768         // 12 waves, 3 per SIMD
#define KT3 3            // k-tiles of 64 -> 192 >= 181
#define FRAGB 1024       // bytes per kt fragment (64 lanes x 16 B)
#define PST 192          // unit stride (wsc, FC)
#define XSTR 1027        // x_s stride (odd -> broadcast reads conflict-free)

typedef __attribute__((ext_vector_type(4))) int   intx4;

#define LOG2E 1.4426950408889634f
// Schraudolph exp2 (balanced sawtooth, |rel err| <= ~3%), clamped to [-20,14]
#define SCH_C  1064992506.0f
#define SCH_LO 897220352.0f
#define SCH_HI 1182433024.0f

__device__ __forceinline__ float exp2_fast(float g) {
    float s = fmaf(g, 8388608.0f, SCH_C);
    s = fminf(fmaxf(s, SCH_LO), SCH_HI);
    return __uint_as_float((unsigned)s);
}
__device__ __forceinline__ float rcpf(float x)   { return __builtin_amdgcn_rcpf(x); }
__device__ __forceinline__ float exp2hw(float x) { return __builtin_amdgcn_exp2f(x); }

// 256 persistent blocks x 4 batch, 12 waves, SINGLE-PHASE / ONE BARRIER per step.
// Wave jt owns unit-tile jt for ALL 3 gates: A = i8 w_hh (regs), B = i8 h
// (LDS frags). After 9 mfma_i32_16x16x64_i8, the C-layout (lane(col,q) reg r =
// unit q*4+r, batch col; cols 4..15 garbage) is redistributed IN-WAVE via DPP
// row_shr:{4,8,12} with bank masks: lane q*16 + r*4 + b  <-  reg r of lane
// q*16 + b. Every lane then holds ONE (unit,batch) triple -> dense dequant +
// gates (r Schraudolph, z/n exact exp = R13 numerics). h bytes re-packed via
// DPP row_shl gathers + v_perm; leader lanes (rr4==0) write one b32 into the
// next frag buffer. No preact LDS round-trip, no second barrier (R13: 57% of
// step time was no-pipe-busy barrier stall).
__launch_bounds__(NTHR, 3)
__global__ void gru_i8(const float* __restrict__ x,
                       const float* __restrict__ w_ih,
                       const float* __restrict__ w_hh,
                       const float* __restrict__ b_ih,
                       const float* __restrict__ b_hh,
                       const float* __restrict__ w_fc,
                       const float* __restrict__ b_fc,
                       float* __restrict__ out) {
    __shared__ __align__(16) char  hfr_s[2 * KT3 * FRAGB];  // 6 KB i8 h dbuf
    __shared__ __align__(16) float x_s[BB * XSTR];          // 16 KB x; reused for FC
    __shared__ float wsc_s[3 * PST];                        // w_hh row scales
    __shared__ volatile char pad_s[57344];                  // total > 80 KB: pin 1 block/CU

    const int tid  = threadIdx.x;
    const int jt   = tid >> 6;          // wave = unit tile 0..11
    const int lane = tid & 63;
    const int col  = lane & 15;
    const int q    = lane >> 4;
    const int b0   = blockIdx.x * BB;
    if (tid == 0) pad_s[0] = 0;

    // ---- A fragments: per-row int8 w_hh, 3 gates x 3 kt (m = jt*16+col) ----
    const int  mu = jt * 16 + col;
    const bool mv = (mu < H);
    intx4 afr[3][KT3];
    #pragma unroll
    for (int g = 0; g < 3; ++g) {
        const float* wrow = w_hh + (size_t)(g * H + (mv ? mu : 0)) * H;
        float rm = 0.0f;
        if (mv) for (int k = 0; k < H; ++k) rm = fmaxf(rm, fabsf(wrow[k]));
        float s    = (rm > 1e-30f) ? rm * (1.0f / 127.0f) : 1.0f;
        float invs = 1.0f / s;
        #pragma unroll
        for (int kt = 0; kt < KT3; ++kt) {
            union { signed char c[16]; intx4 v; } uu;
            #pragma unroll
            for (int e = 0; e < 16; ++e) {
                int k = kt * 64 + q * 16 + e;
                float v = (mv && k < H) ? wrow[k] * invs : 0.0f;
                v = fminf(fmaxf(rintf(v), -127.0f), 127.0f);
                uu.c[e] = (signed char)(int)v;
            }
            afr[g][kt] = uu.v;
        }
        if (q == 0) wsc_s[g * PST + mu] = s;
    }

    // ---- stage x (stride 1027); zero h frag buffers ----
    for (int i = tid; i < BB * T_LEN; i += NTHR) {
        int bb = i >> 10, t = i & 1023;
        x_s[bb * XSTR + t] = x[(size_t)b0 * T_LEN + i];
    }
    {
        int* hz = (int*)hfr_s;
        for (int i = tid; i < 2 * KT3 * FRAGB / 4; i += NTHR) hz[i] = 0;
    }
    __syncthreads();   // wsc_s ready

    // ---- dense per-lane identity after DPP redistribute ----
    const int  rr4 = (col >> 2) & 3;       // reg index this lane receives
    const int  b   = col & 3;              // batch
    const int  u   = jt * 16 + q * 4 + rr4;  // unit
    const bool jv  = (u < H);
    const float dqR = -LOG2E * wsc_s[0 * PST + u] * (1.0f / 127.0f);
    const float dqZ = -LOG2E * wsc_s[1 * PST + u] * (1.0f / 127.0f);
    const float dqN =  2.0f * LOG2E * wsc_s[2 * PST + u] * (1.0f / 127.0f);
    const float baseR = jv ? -LOG2E * (b_ih[u] + b_hh[u])             : 0.0f;
    const float baseZ = jv ? -LOG2E * (b_ih[H + u] + b_hh[H + u])     : 0.0f;
    const float baseN = jv ?  2.0f * LOG2E * b_hh[2 * H + u]          : 0.0f;
    const float wrS = jv ? -LOG2E * w_ih[u]                : 0.0f;
    const float wzS = jv ? -LOG2E * w_ih[H + u]            : 0.0f;
    const float wnS = jv ?  2.0f * LOG2E * w_ih[2 * H + u] : 0.0f;
    const float bnI = jv ?  2.0f * LOG2E * b_ih[2 * H + u] : 0.0f;
    // leader (rr4==0) packs 4 units' bytes and writes one b32
    const int woffB = (jt >> 2) * FRAGB + (((jt & 3) * 16 + b) * 16) + q * 4;
    const int rbase = lane * 16;

    float h = 0.0f;

    auto step = [&](const char* rb, char* wb, int t) {
        intx4 bf[KT3];
        #pragma unroll
        for (int kt = 0; kt < KT3; ++kt)
            bf[kt] = *(const intx4*)(rb + kt * FRAGB + rbase);
        intx4 aR = {0,0,0,0}, aZ = {0,0,0,0}, aN = {0,0,0,0};
        #pragma unroll
        for (int kt = 0; kt < KT3; ++kt) {
            aR = __builtin_amdgcn_mfma_i32_16x16x64_i8(afr[0][kt], bf[kt], aR, 0, 0, 0);
            aZ = __builtin_amdgcn_mfma_i32_16x16x64_i8(afr[1][kt], bf[kt], aZ, 0, 0, 0);
            aN = __builtin_amdgcn_mfma_i32_16x16x64_i8(afr[2][kt], bf[kt], aN, 0, 0, 0);
        }

        // ---- DPP redistribute: lane q*16+r*4+b <- reg r of lane q*16+b ----
        // row_shr:4r (0x110+4r), bank_mask 1<<r (banks of 4 lanes per row)
        int vR = aR[0], vZ = aZ[0], vN = aN[0];
        vR = __builtin_amdgcn_update_dpp(vR, aR[1], 0x114, 0xF, 0x2, false);
        vR = __builtin_amdgcn_update_dpp(vR, aR[2], 0x118, 0xF, 0x4, false);
        vR = __builtin_amdgcn_update_dpp(vR, aR[3], 0x11C, 0xF, 0x8, false);
        vZ = __builtin_amdgcn_update_dpp(vZ, aZ[1], 0x114, 0xF, 0x2, false);
        vZ = __builtin_amdgcn_update_dpp(vZ, aZ[2], 0x118, 0xF, 0x4, false);
        vZ = __builtin_amdgcn_update_dpp(vZ, aZ[3], 0x11C, 0xF, 0x8, false);
        vN = __builtin_amdgcn_update_dpp(vN, aN[1], 0x114, 0xF, 0x2, false);
        vN = __builtin_amdgcn_update_dpp(vN, aN[2], 0x118, 0xF, 0x4, false);
        vN = __builtin_amdgcn_update_dpp(vN, aN[3], 0x11C, 0xF, 0x8, false);

        // ---- dense dequant + gates (R13 numerics) ----
        float pR = fmaf((float)vR, dqR, baseR);
        float pZ = fmaf((float)vZ, dqZ, baseZ);
        float pN = fmaf((float)vN, dqN, baseN);
        float xv = x_s[b * XSTR + t];

        float er = exp2_fast(fmaf(xv, wrS, pR));
        float ez = exp2hw(fminf(fmaf(xv, wzS, pZ), 14.0f));
        float dR = 1.0f + er, dZ = 1.0f + ez;
        float qq = rcpf(dR * dZ);
        float rr = qq * dZ, zz = qq * dR;
        float gn = fmaf(rr, pN, fmaf(xv, wnS, bnI));
        float en = exp2hw(fminf(gn, 30.0f));
        float nn = fmaf(-2.0f, rcpf(1.0f + en), 1.0f);  // tanh
        h = fmaf(zz, h - nn, nn);                        // |h|<1

        int iq = (int)rintf(h * 127.0f);
        int hq = jv ? (iq & 255) : 0;
        // ---- DPP gather (row_shl:4r) + perm pack: bytes r=0..3 ----
        int t1 = __builtin_amdgcn_update_dpp(0, hq, 0x104, 0xF, 0xF, true);
        int t2 = __builtin_amdgcn_update_dpp(0, hq, 0x108, 0xF, 0xF, true);
        int t3 = __builtin_amdgcn_update_dpp(0, hq, 0x10C, 0xF, 0xF, true);
        int p01 = __builtin_amdgcn_perm(t1, hq, 0x05010400);  // hq.b0 | t1.b0<<8 | ...
        int p23 = __builtin_amdgcn_perm(t3, t2, 0x05010400);  // t2.b0 | t3.b0<<8 | ...
        int pk  = __builtin_amdgcn_perm(p23, p01, 0x05040100);
        if (rr4 == 0)
            *(int*)(wb + woffB) = pk;
        __syncthreads();   // the ONLY barrier per step
    };

    char* buf0 = hfr_s;
    char* buf1 = hfr_s + KT3 * FRAGB;
    for (int t = 0; t < T_LEN; t += 2) {
        step(buf0, buf1, t);
        step(buf1, buf0, t + 1);
    }

    // ---- final FC: publish h (f32) into x_s (x done), 40 lanes reduce ----
    __syncthreads();
    if (u < PST) x_s[b * PST + u] = h;
    __syncthreads();
    if (tid < BB * 10) {
        int bb = tid / 10, c = tid % 10;
        float acc = b_fc[c];
        for (int k = 0; k < H; ++k)
            acc = fmaf(x_s[bb * PST + k], w_fc[c * H + k], acc);
        out[(b0 + bb) * 10 + c] = acc;
    }
}

extern "C" void kernel_launch(void* const* d_in, const int* in_sizes, int n_in,
                              void* d_out, int out_size, void* d_ws, size_t ws_size,
                              hipStream_t stream) {
    const float* x    = (const float*)d_in[0];
    const float* w_ih = (const float*)d_in[1];
    const float* w_hh = (const float*)d_in[2];
    const float* b_ih = (const float*)d_in[3];
    const float* b_hh = (const float*)d_in[4];
    const float* w_fc = (const float*)d_in[5];
    const float* b_fc = (const float*)d_in[6];
    float* out = (float*)d_out;

    gru_i8<<<NBLK, NTHR, 0, stream>>>(x, w_ih, w_hh, b_ih, b_hh, w_fc, b_fc, out);
}